// Round 1
// baseline (1924.126 us; speedup 1.0000x reference)
//
#include <hip/hip_runtime.h>
#include <hip/hip_bf16.h>
#include <math.h>
#include <stdint.h>

// Problem constants (derived from in_sizes at launch, but layout fixed):
// N = 32768 nodes, D = 256 features, E = 524288 edges, L = 3 layers,
// K = 16384 (top-k), C = 11 classes.

#define D_FEAT 256

// ---------------------------------------------------------------------------
// 1. concat f0,f1 -> x0 [N][256]
// ---------------------------------------------------------------------------
__global__ __launch_bounds__(256) void concat_kernel(const float* __restrict__ f0,
                                                     const float* __restrict__ f1,
                                                     float* __restrict__ x,
                                                     int N) {
    int gid = blockIdx.x * blockDim.x + threadIdx.x;  // one float4 per thread
    int total = N * 64;                               // 64 float4 per row
    if (gid >= total) return;
    int n = gid >> 6;
    int q = gid & 63;
    float4 v;
    if (q < 32) v = *(const float4*)(f0 + (size_t)n * 128 + q * 4);
    else        v = *(const float4*)(f1 + (size_t)n * 128 + (q - 32) * 4);
    *(float4*)(x + (size_t)n * 256 + q * 4) = v;
}

// ---------------------------------------------------------------------------
// 2a. histogram of dst
// ---------------------------------------------------------------------------
__global__ __launch_bounds__(256) void count_kernel(const int* __restrict__ dst,
                                                    int* __restrict__ counts, int E) {
    int e = blockIdx.x * blockDim.x + threadIdx.x;
    if (e < E) atomicAdd(&counts[dst[e]], 1);
}

// ---------------------------------------------------------------------------
// 2b. exclusive scan of counts -> offsets[N+1]; zero counts (reused as cursor)
//     single block of 1024 threads, each handles 32 entries. N must be 32768.
// ---------------------------------------------------------------------------
__global__ __launch_bounds__(1024) void scan_kernel(int* __restrict__ counts,
                                                    int* __restrict__ offs,
                                                    int N, int E) {
    __shared__ int s[1024];
    int t = threadIdx.x;
    int base = t * 32;
    int local[32];
    int sum = 0;
    #pragma unroll
    for (int j = 0; j < 32; ++j) { local[j] = counts[base + j]; sum += local[j]; }
    s[t] = sum;
    __syncthreads();
    for (int off = 1; off < 1024; off <<= 1) {
        int other = (t >= off) ? s[t - off] : 0;
        __syncthreads();
        s[t] += other;
        __syncthreads();
    }
    int run = s[t] - sum;  // exclusive base for this thread
    #pragma unroll
    for (int j = 0; j < 32; ++j) {
        offs[base + j] = run;
        run += local[j];
        counts[base + j] = 0;   // reset: reused as cursor in fill_kernel
    }
    if (t == 1023) offs[N] = E;
}

// ---------------------------------------------------------------------------
// 2c. scatter edge ids into CSR buckets (within-bucket order nondeterministic,
//     fixed by 2d's sort)
// ---------------------------------------------------------------------------
__global__ __launch_bounds__(256) void fill_kernel(const int* __restrict__ dst,
                                                   const int* __restrict__ offs,
                                                   int* __restrict__ cursor,
                                                   int* __restrict__ csr, int E) {
    int e = blockIdx.x * blockDim.x + threadIdx.x;
    if (e >= E) return;
    int d = dst[e];
    int pos = offs[d] + atomicAdd(&cursor[d], 1);
    csr[pos] = e;
}

// ---------------------------------------------------------------------------
// 2d. per-bucket insertion sort by edge id (deterministic order), then map
//     edge id -> src node id in place.
// ---------------------------------------------------------------------------
__global__ __launch_bounds__(256) void bsort_kernel(int* __restrict__ csr,
                                                    const int* __restrict__ offs,
                                                    const int* __restrict__ src,
                                                    int N) {
    int i = blockIdx.x * blockDim.x + threadIdx.x;
    if (i >= N) return;
    int beg = offs[i], end = offs[i + 1];
    for (int a = beg + 1; a < end; ++a) {
        int v = csr[a];
        int b = a - 1;
        while (b >= beg && csr[b] > v) { csr[b + 1] = csr[b]; --b; }
        csr[b + 1] = v;
    }
    for (int p = beg; p < end; ++p) csr[p] = src[csr[p]];
}

// ---------------------------------------------------------------------------
// 3. segment sum: agg[n][:] = sum over csr bucket of x[src][:]
//    one wave (64 lanes) per node, 4 waves / block, float4 per lane.
// ---------------------------------------------------------------------------
__global__ __launch_bounds__(256) void segsum_kernel(const float* __restrict__ X,
                                                     const int* __restrict__ csr,
                                                     const int* __restrict__ offs,
                                                     float* __restrict__ AGG, int N) {
    int w = threadIdx.x >> 6;
    int lane = threadIdx.x & 63;
    int n = blockIdx.x * 4 + w;
    if (n >= N) return;
    int beg = offs[n], end = offs[n + 1];
    float4 acc = make_float4(0.f, 0.f, 0.f, 0.f);
    for (int p = beg; p < end; ++p) {
        int s = csr[p];
        float4 v = *(const float4*)(X + (size_t)s * 256 + lane * 4);
        acc.x += v.x; acc.y += v.y; acc.z += v.z; acc.w += v.w;
    }
    *(float4*)(AGG + (size_t)n * 256 + lane * 4) = acc;
}

// ---------------------------------------------------------------------------
// 4. fused GEMM: Y = relu(X @ W1 + G @ W2 + bias)   [N,256] x [256,256]
//    64x64 tile, BK=16, 256 threads, 4x4 micro-tile per thread.
// ---------------------------------------------------------------------------
#define BM 64
#define BN 64
#define BK 16
__global__ __launch_bounds__(256) void gemm_two_kernel(const float* __restrict__ X,
                                                       const float* __restrict__ G,
                                                       const float* __restrict__ W1,
                                                       const float* __restrict__ W2,
                                                       const float* __restrict__ bias,
                                                       float* __restrict__ Y,
                                                       int N, int do_relu) {
    __shared__ float As[BK][BM + 4];
    __shared__ float Ws[BK][BN + 4];
    const int tid = threadIdx.x;
    const int tcol = tid & 15;          // 0..15 (output col group)
    const int trow = tid >> 4;          // 0..15 (output row group)
    const int rowBase = blockIdx.y * BM;
    const int colBase = blockIdx.x * BN;

    const int lrow = tid >> 2;          // 0..63  A tile row
    const int lk   = (tid & 3) * 4;     // 0,4,8,12  A tile k (float4)
    const int wk   = tid >> 4;          // 0..15  W tile k row
    const int wcol = (tid & 15) * 4;    // W tile col (float4)

    float acc[4][4];
    #pragma unroll
    for (int i = 0; i < 4; ++i)
        #pragma unroll
        for (int j = 0; j < 4; ++j) acc[i][j] = 0.f;

    for (int kt = 0; kt < 512 / BK; ++kt) {
        int kb = kt * BK;
        const float* Asrc; const float* Wsrc; int kloc;
        if (kb < 256) { Asrc = X; Wsrc = W1; kloc = kb; }
        else          { Asrc = G; Wsrc = W2; kloc = kb - 256; }
        float4 av = *(const float4*)(Asrc + (size_t)(rowBase + lrow) * 256 + kloc + lk);
        float4 wv = *(const float4*)(Wsrc + (size_t)(kloc + wk) * 256 + colBase + wcol);
        __syncthreads();   // previous tile fully consumed
        As[lk + 0][lrow] = av.x;
        As[lk + 1][lrow] = av.y;
        As[lk + 2][lrow] = av.z;
        As[lk + 3][lrow] = av.w;
        *(float4*)&Ws[wk][wcol] = wv;
        __syncthreads();
        #pragma unroll
        for (int kk = 0; kk < BK; ++kk) {
            float4 a = *(const float4*)&As[kk][trow * 4];
            float4 w = *(const float4*)&Ws[kk][tcol * 4];
            acc[0][0] += a.x * w.x; acc[0][1] += a.x * w.y; acc[0][2] += a.x * w.z; acc[0][3] += a.x * w.w;
            acc[1][0] += a.y * w.x; acc[1][1] += a.y * w.y; acc[1][2] += a.y * w.z; acc[1][3] += a.y * w.w;
            acc[2][0] += a.z * w.x; acc[2][1] += a.z * w.y; acc[2][2] += a.z * w.z; acc[2][3] += a.z * w.w;
            acc[3][0] += a.w * w.x; acc[3][1] += a.w * w.y; acc[3][2] += a.w * w.z; acc[3][3] += a.w * w.w;
        }
    }
    #pragma unroll
    for (int i = 0; i < 4; ++i) {
        int row = rowBase + trow * 4 + i;
        #pragma unroll
        for (int j = 0; j < 4; ++j) {
            int col = colBase + tcol * 4 + j;
            float v = acc[i][j] + bias[col];
            if (do_relu) v = fmaxf(v, 0.f);
            Y[(size_t)row * 256 + col] = v;
        }
    }
}

// ---------------------------------------------------------------------------
// 5. pooling score: sc[n] = x3[n].Wpr + agg3[n].Wpn + bp   (double accum)
//    one wave per node.
// ---------------------------------------------------------------------------
__global__ __launch_bounds__(256) void score_kernel(const float* __restrict__ X3,
                                                    const float* __restrict__ AGG,
                                                    const float* __restrict__ Wpr,
                                                    const float* __restrict__ Wpn,
                                                    const float* __restrict__ bp,
                                                    double* __restrict__ sc, int N) {
    int w = threadIdx.x >> 6;
    int lane = threadIdx.x & 63;
    int n = blockIdx.x * 4 + w;
    if (n >= N) return;
    float4 xv = *(const float4*)(X3 + (size_t)n * 256 + lane * 4);
    float4 av = *(const float4*)(AGG + (size_t)n * 256 + lane * 4);
    float4 wr = *(const float4*)(Wpr + lane * 4);
    float4 wn = *(const float4*)(Wpn + lane * 4);
    double part = (double)xv.x * wr.x + (double)xv.y * wr.y +
                  (double)xv.z * wr.z + (double)xv.w * wr.w +
                  (double)av.x * wn.x + (double)av.y * wn.y +
                  (double)av.z * wn.z + (double)av.w * wn.w;
    #pragma unroll
    for (int o = 32; o > 0; o >>= 1) part += __shfl_down(part, o, 64);
    if (lane == 0) sc[n] = part + (double)bp[0];
}

// ---------------------------------------------------------------------------
// 6. exact rank: rank[i] = #{ j : s_j > s_i  or (s_j == s_i and j < i) }
//    Bijective -> rank is the output row. K = N/2 rows kept.
// ---------------------------------------------------------------------------
__global__ __launch_bounds__(256) void rank_kernel(const double* __restrict__ sc,
                                                   int* __restrict__ perm,
                                                   double* __restrict__ topd,
                                                   int N, int K) {
    __shared__ double ch[2048];
    int i = blockIdx.x * 256 + threadIdx.x;
    double me = sc[i];
    int cnt = 0;
    for (int base = 0; base < N; base += 2048) {
        for (int t = threadIdx.x; t < 2048; t += 256) ch[t] = sc[base + t];
        __syncthreads();
        #pragma unroll 4
        for (int u = 0; u < 2048; ++u) {
            double s = ch[u];
            int j = base + u;
            cnt += (s > me) || (s == me && j < i);
        }
        __syncthreads();
    }
    if (cnt < K) { perm[cnt] = i; topd[cnt] = me; }
}

// ---------------------------------------------------------------------------
// 7. head: out[r] = relu(x3[perm[r]] * tanh(score_r)) @ Wc + bc   (f64 accum)
//    one wave per row.
// ---------------------------------------------------------------------------
__global__ __launch_bounds__(256) void out_kernel(const float* __restrict__ X3,
                                                  const int* __restrict__ perm,
                                                  const double* __restrict__ topd,
                                                  const float* __restrict__ Wc,
                                                  const float* __restrict__ bc,
                                                  float* __restrict__ out, int K) {
    int w = threadIdx.x >> 6;
    int lane = threadIdx.x & 63;
    int r = blockIdx.x * 4 + w;
    if (r >= K) return;
    int p = perm[r];
    double t = tanh(topd[r]);
    float4 xv = *(const float4*)(X3 + (size_t)p * 256 + lane * 4);
    double xp[4];
    xp[0] = (double)xv.x * t; xp[1] = (double)xv.y * t;
    xp[2] = (double)xv.z * t; xp[3] = (double)xv.w * t;
    #pragma unroll
    for (int j = 0; j < 4; ++j) xp[j] = xp[j] > 0.0 ? xp[j] : 0.0;
    double acc[11];
    #pragma unroll
    for (int c = 0; c < 11; ++c) acc[c] = 0.0;
    #pragma unroll
    for (int j = 0; j < 4; ++j) {
        const float* wrow = Wc + (size_t)(lane * 4 + j) * 11;
        #pragma unroll
        for (int c = 0; c < 11; ++c) acc[c] += xp[j] * (double)wrow[c];
    }
    #pragma unroll
    for (int c = 0; c < 11; ++c) {
        double v = acc[c];
        #pragma unroll
        for (int o = 32; o > 0; o >>= 1) v += __shfl_down(v, o, 64);
        if (lane == 0) out[(size_t)r * 11 + c] = (float)(v + (double)bc[c]);
    }
}

// ---------------------------------------------------------------------------
// launch
// ---------------------------------------------------------------------------
extern "C" void kernel_launch(void* const* d_in, const int* in_sizes, int n_in,
                              void* d_out, int out_size, void* d_ws, size_t ws_size,
                              hipStream_t stream) {
    const float* f0  = (const float*)d_in[0];
    const float* f1  = (const float*)d_in[1];
    const int*   ei  = (const int*)d_in[2];
    const float* Wr  = (const float*)d_in[3];
    const float* Wn  = (const float*)d_in[4];
    const float* b   = (const float*)d_in[5];
    const float* Wpr = (const float*)d_in[6];
    const float* Wpn = (const float*)d_in[7];
    const float* bp  = (const float*)d_in[8];
    const float* Wc  = (const float*)d_in[9];
    const float* bc  = (const float*)d_in[10];
    float* out = (float*)d_out;

    const int N = in_sizes[0] / 128;   // 32768
    const int E = in_sizes[2] / 2;     // 524288
    const int K = (N + 1) / 2;         // 16384
    const int L = in_sizes[5] / 256;   // 3 layers

    const int* src = ei;
    const int* dst = ei + E;

    // workspace layout (256B aligned slices)
    char* p = (char*)d_ws;
    auto take = [&](size_t bytes) {
        char* r = p;
        p += (bytes + 255) & ~(size_t)255;
        return r;
    };
    float*  xA     = (float*)take((size_t)N * 256 * 4);
    float*  xB     = (float*)take((size_t)N * 256 * 4);
    float*  agg    = (float*)take((size_t)N * 256 * 4);
    int*    counts = (int*)take((size_t)N * 4);
    int*    offs   = (int*)take((size_t)(N + 1) * 4);
    int*    csr    = (int*)take((size_t)E * 4);
    double* sc     = (double*)take((size_t)N * 8);
    double* topd   = (double*)take((size_t)K * 8);
    int*    perm   = (int*)take((size_t)K * 4);
    (void)ws_size;

    hipMemsetAsync(counts, 0, (size_t)N * 4, stream);

    concat_kernel<<<(N * 64 + 255) / 256, 256, 0, stream>>>(f0, f1, xA, N);
    count_kernel<<<(E + 255) / 256, 256, 0, stream>>>(dst, counts, E);
    scan_kernel<<<1, 1024, 0, stream>>>(counts, offs, N, E);
    fill_kernel<<<(E + 255) / 256, 256, 0, stream>>>(dst, offs, counts, csr, E);
    bsort_kernel<<<(N + 255) / 256, 256, 0, stream>>>(csr, offs, src, N);

    float* xcur = xA;
    float* xnext = xB;
    for (int i = 0; i < L; ++i) {
        segsum_kernel<<<N / 4, 256, 0, stream>>>(xcur, csr, offs, agg, N);
        gemm_two_kernel<<<dim3(256 / BN, N / BM), 256, 0, stream>>>(
            xcur, agg, Wr + (size_t)i * 65536, Wn + (size_t)i * 65536,
            b + (size_t)i * 256, xnext, N, 1);
        float* tmp = xcur; xcur = xnext; xnext = tmp;
    }
    // xcur == x3
    segsum_kernel<<<N / 4, 256, 0, stream>>>(xcur, csr, offs, agg, N);
    score_kernel<<<N / 4, 256, 0, stream>>>(xcur, agg, Wpr, Wpn, bp, sc, N);
    rank_kernel<<<N / 256, 256, 0, stream>>>(sc, perm, topd, N, K);
    out_kernel<<<K / 4, 256, 0, stream>>>(xcur, perm, topd, Wc, bc, out, K);
}

// Round 2
// 999.959 us; speedup vs baseline: 1.9242x; 1.9242x over previous
//
#include <hip/hip_runtime.h>
#include <hip/hip_bf16.h>
#include <math.h>
#include <stdint.h>

// N = 32768 nodes, D = 256 features, E = 524288 edges, L = 3 layers,
// K = 16384 (top-k), C = 11 classes.

#define D_FEAT 256

// ---------------------------------------------------------------------------
// 1. concat f0,f1 -> x0 [N][256]
// ---------------------------------------------------------------------------
__global__ __launch_bounds__(256) void concat_kernel(const float* __restrict__ f0,
                                                     const float* __restrict__ f1,
                                                     float* __restrict__ x,
                                                     int N) {
    int gid = blockIdx.x * blockDim.x + threadIdx.x;  // one float4 per thread
    int total = N * 64;                               // 64 float4 per row
    if (gid >= total) return;
    int n = gid >> 6;
    int q = gid & 63;
    float4 v;
    if (q < 32) v = *(const float4*)(f0 + (size_t)n * 128 + q * 4);
    else        v = *(const float4*)(f1 + (size_t)n * 128 + (q - 32) * 4);
    *(float4*)(x + (size_t)n * 256 + q * 4) = v;
}

// ---------------------------------------------------------------------------
// 2a. histogram of dst
// ---------------------------------------------------------------------------
__global__ __launch_bounds__(256) void count_kernel(const int* __restrict__ dst,
                                                    int* __restrict__ counts, int E) {
    int e = blockIdx.x * blockDim.x + threadIdx.x;
    if (e < E) atomicAdd(&counts[dst[e]], 1);
}

// ---------------------------------------------------------------------------
// 2b. exclusive scan of counts -> offsets[N+1]; zero counts (reused as cursor)
// ---------------------------------------------------------------------------
__global__ __launch_bounds__(1024) void scan_kernel(int* __restrict__ counts,
                                                    int* __restrict__ offs,
                                                    int N, int E) {
    __shared__ int s[1024];
    int t = threadIdx.x;
    int base = t * 32;
    int local[32];
    int sum = 0;
    #pragma unroll
    for (int j = 0; j < 32; ++j) { local[j] = counts[base + j]; sum += local[j]; }
    s[t] = sum;
    __syncthreads();
    for (int off = 1; off < 1024; off <<= 1) {
        int other = (t >= off) ? s[t - off] : 0;
        __syncthreads();
        s[t] += other;
        __syncthreads();
    }
    int run = s[t] - sum;  // exclusive base for this thread
    #pragma unroll
    for (int j = 0; j < 32; ++j) {
        offs[base + j] = run;
        run += local[j];
        counts[base + j] = 0;   // reset: reused as cursor in fill_kernel
    }
    if (t == 1023) offs[N] = E;
}

// ---------------------------------------------------------------------------
// 2c. scatter edge ids into CSR buckets
// ---------------------------------------------------------------------------
__global__ __launch_bounds__(256) void fill_kernel(const int* __restrict__ dst,
                                                   const int* __restrict__ offs,
                                                   int* __restrict__ cursor,
                                                   int* __restrict__ csr, int E) {
    int e = blockIdx.x * blockDim.x + threadIdx.x;
    if (e >= E) return;
    int d = dst[e];
    int pos = offs[d] + atomicAdd(&cursor[d], 1);
    csr[pos] = e;
}

// ---------------------------------------------------------------------------
// 2d. per-bucket insertion sort by edge id (deterministic), map edge->src
// ---------------------------------------------------------------------------
__global__ __launch_bounds__(256) void bsort_kernel(int* __restrict__ csr,
                                                    const int* __restrict__ offs,
                                                    const int* __restrict__ src,
                                                    int N) {
    int i = blockIdx.x * blockDim.x + threadIdx.x;
    if (i >= N) return;
    int beg = offs[i], end = offs[i + 1];
    for (int a = beg + 1; a < end; ++a) {
        int v = csr[a];
        int b = a - 1;
        while (b >= beg && csr[b] > v) { csr[b + 1] = csr[b]; --b; }
        csr[b + 1] = v;
    }
    for (int p = beg; p < end; ++p) csr[p] = src[csr[p]];
}

// ---------------------------------------------------------------------------
// 3. segment sum: agg[n][:] = sum over csr bucket of x[src][:]
// ---------------------------------------------------------------------------
__global__ __launch_bounds__(256) void segsum_kernel(const float* __restrict__ X,
                                                     const int* __restrict__ csr,
                                                     const int* __restrict__ offs,
                                                     float* __restrict__ AGG, int N) {
    int w = threadIdx.x >> 6;
    int lane = threadIdx.x & 63;
    int n = blockIdx.x * 4 + w;
    if (n >= N) return;
    int beg = offs[n], end = offs[n + 1];
    float4 acc = make_float4(0.f, 0.f, 0.f, 0.f);
    for (int p = beg; p < end; ++p) {
        int s = csr[p];
        float4 v = *(const float4*)(X + (size_t)s * 256 + lane * 4);
        acc.x += v.x; acc.y += v.y; acc.z += v.z; acc.w += v.w;
    }
    *(float4*)(AGG + (size_t)n * 256 + lane * 4) = acc;
}

// ---------------------------------------------------------------------------
// 4. fused GEMM: Y = relu(X @ W1 + G @ W2 + bias)   [N,256] x [256,256]
// ---------------------------------------------------------------------------
#define BM 64
#define BN 64
#define BK 16
__global__ __launch_bounds__(256) void gemm_two_kernel(const float* __restrict__ X,
                                                       const float* __restrict__ G,
                                                       const float* __restrict__ W1,
                                                       const float* __restrict__ W2,
                                                       const float* __restrict__ bias,
                                                       float* __restrict__ Y,
                                                       int N, int do_relu) {
    __shared__ float As[BK][BM + 4];
    __shared__ float Ws[BK][BN + 4];
    const int tid = threadIdx.x;
    const int tcol = tid & 15;          // 0..15 (output col group)
    const int trow = tid >> 4;          // 0..15 (output row group)
    const int rowBase = blockIdx.y * BM;
    const int colBase = blockIdx.x * BN;

    const int lrow = tid >> 2;          // 0..63  A tile row
    const int lk   = (tid & 3) * 4;     // 0,4,8,12  A tile k (float4)
    const int wk   = tid >> 4;          // 0..15  W tile k row
    const int wcol = (tid & 15) * 4;    // W tile col (float4)

    float acc[4][4];
    #pragma unroll
    for (int i = 0; i < 4; ++i)
        #pragma unroll
        for (int j = 0; j < 4; ++j) acc[i][j] = 0.f;

    for (int kt = 0; kt < 512 / BK; ++kt) {
        int kb = kt * BK;
        const float* Asrc; const float* Wsrc; int kloc;
        if (kb < 256) { Asrc = X; Wsrc = W1; kloc = kb; }
        else          { Asrc = G; Wsrc = W2; kloc = kb - 256; }
        float4 av = *(const float4*)(Asrc + (size_t)(rowBase + lrow) * 256 + kloc + lk);
        float4 wv = *(const float4*)(Wsrc + (size_t)(kloc + wk) * 256 + colBase + wcol);
        __syncthreads();   // previous tile fully consumed
        As[lk + 0][lrow] = av.x;
        As[lk + 1][lrow] = av.y;
        As[lk + 2][lrow] = av.z;
        As[lk + 3][lrow] = av.w;
        *(float4*)&Ws[wk][wcol] = wv;
        __syncthreads();
        #pragma unroll
        for (int kk = 0; kk < BK; ++kk) {
            float4 a = *(const float4*)&As[kk][trow * 4];
            float4 w = *(const float4*)&Ws[kk][tcol * 4];
            acc[0][0] += a.x * w.x; acc[0][1] += a.x * w.y; acc[0][2] += a.x * w.z; acc[0][3] += a.x * w.w;
            acc[1][0] += a.y * w.x; acc[1][1] += a.y * w.y; acc[1][2] += a.y * w.z; acc[1][3] += a.y * w.w;
            acc[2][0] += a.z * w.x; acc[2][1] += a.z * w.y; acc[2][2] += a.z * w.z; acc[2][3] += a.z * w.w;
            acc[3][0] += a.w * w.x; acc[3][1] += a.w * w.y; acc[3][2] += a.w * w.z; acc[3][3] += a.w * w.w;
        }
    }
    #pragma unroll
    for (int i = 0; i < 4; ++i) {
        int row = rowBase + trow * 4 + i;
        #pragma unroll
        for (int j = 0; j < 4; ++j) {
            int col = colBase + tcol * 4 + j;
            float v = acc[i][j] + bias[col];
            if (do_relu) v = fmaxf(v, 0.f);
            Y[(size_t)row * 256 + col] = v;
        }
    }
}

// ---------------------------------------------------------------------------
// 5. pooling score + order-preserving uint64 key
// ---------------------------------------------------------------------------
__global__ __launch_bounds__(256) void score_kernel(const float* __restrict__ X3,
                                                    const float* __restrict__ AGG,
                                                    const float* __restrict__ Wpr,
                                                    const float* __restrict__ Wpn,
                                                    const float* __restrict__ bp,
                                                    double* __restrict__ sc,
                                                    unsigned long long* __restrict__ keys,
                                                    int N) {
    int w = threadIdx.x >> 6;
    int lane = threadIdx.x & 63;
    int n = blockIdx.x * 4 + w;
    if (n >= N) return;
    float4 xv = *(const float4*)(X3 + (size_t)n * 256 + lane * 4);
    float4 av = *(const float4*)(AGG + (size_t)n * 256 + lane * 4);
    float4 wr = *(const float4*)(Wpr + lane * 4);
    float4 wn = *(const float4*)(Wpn + lane * 4);
    double part = (double)xv.x * wr.x + (double)xv.y * wr.y +
                  (double)xv.z * wr.z + (double)xv.w * wr.w +
                  (double)av.x * wn.x + (double)av.y * wn.y +
                  (double)av.z * wn.z + (double)av.w * wn.w;
    #pragma unroll
    for (int o = 32; o > 0; o >>= 1) part += __shfl_down(part, o, 64);
    if (lane == 0) {
        double s = part + (double)bp[0];
        sc[n] = s;
        long long sb = __double_as_longlong(s);
        unsigned long long k = (sb < 0)
            ? ~(unsigned long long)sb
            : ((unsigned long long)sb | 0x8000000000000000ULL);
        keys[n] = k;
    }
}

// ---------------------------------------------------------------------------
// 6a. tiled exact rank-count on uint64 keys.
//     Block covers TI=1024 i (4 regs/thread) x TJ=2048 j (LDS).
//     Off-diagonal blocks collapse the tie-break to >= / > (1 cmp/compare).
// ---------------------------------------------------------------------------
#define TI 1024
#define TJ 2048
__global__ __launch_bounds__(256) void rank_count_kernel(
        const unsigned long long* __restrict__ keys,
        int* __restrict__ rankcnt, int N) {
    __shared__ unsigned long long sk[TJ];
    const int tid = threadIdx.x;
    const int ibase = blockIdx.y * TI;
    const int jbase = blockIdx.x * TJ;

    unsigned long long ki[4];
    int ir[4];
    #pragma unroll
    for (int r = 0; r < 4; ++r) {
        ir[r] = ibase + r * 256 + tid;
        ki[r] = keys[ir[r]];
    }
    for (int t = tid; t < TJ; t += 256) sk[t] = keys[jbase + t];
    __syncthreads();

    int cnt[4] = {0, 0, 0, 0};
    if (jbase + TJ <= ibase) {
        // all j < i : tie counts -> kj >= ki
        #pragma unroll 8
        for (int u = 0; u < TJ; ++u) {
            unsigned long long kj = sk[u];
            #pragma unroll
            for (int r = 0; r < 4; ++r) cnt[r] += (kj >= ki[r]);
        }
    } else if (jbase >= ibase + TI) {
        // all j > i : tie doesn't count -> kj > ki
        #pragma unroll 8
        for (int u = 0; u < TJ; ++u) {
            unsigned long long kj = sk[u];
            #pragma unroll
            for (int r = 0; r < 4; ++r) cnt[r] += (kj > ki[r]);
        }
    } else {
        // diagonal: full three-term compare
        #pragma unroll 4
        for (int u = 0; u < TJ; ++u) {
            unsigned long long kj = sk[u];
            int j = jbase + u;
            #pragma unroll
            for (int r = 0; r < 4; ++r)
                cnt[r] += (kj > ki[r]) || (kj == ki[r] && j < ir[r]);
        }
    }
    #pragma unroll
    for (int r = 0; r < 4; ++r) atomicAdd(&rankcnt[ir[r]], cnt[r]);
}

// ---------------------------------------------------------------------------
// 6b. scatter by rank
// ---------------------------------------------------------------------------
__global__ __launch_bounds__(256) void rank_scatter_kernel(
        const int* __restrict__ rankcnt,
        const double* __restrict__ sc,
        int* __restrict__ perm,
        double* __restrict__ topd, int N, int K) {
    int i = blockIdx.x * blockDim.x + threadIdx.x;
    if (i >= N) return;
    int rank = rankcnt[i];
    if (rank < K) { perm[rank] = i; topd[rank] = sc[i]; }
}

// ---------------------------------------------------------------------------
// 7. head: out[r] = relu(x3[perm[r]] * tanh(score_r)) @ Wc + bc  (f64 accum)
// ---------------------------------------------------------------------------
__global__ __launch_bounds__(256) void out_kernel(const float* __restrict__ X3,
                                                  const int* __restrict__ perm,
                                                  const double* __restrict__ topd,
                                                  const float* __restrict__ Wc,
                                                  const float* __restrict__ bc,
                                                  float* __restrict__ out, int K) {
    int w = threadIdx.x >> 6;
    int lane = threadIdx.x & 63;
    int r = blockIdx.x * 4 + w;
    if (r >= K) return;
    int p = perm[r];
    double t = tanh(topd[r]);
    float4 xv = *(const float4*)(X3 + (size_t)p * 256 + lane * 4);
    double xp[4];
    xp[0] = (double)xv.x * t; xp[1] = (double)xv.y * t;
    xp[2] = (double)xv.z * t; xp[3] = (double)xv.w * t;
    #pragma unroll
    for (int j = 0; j < 4; ++j) xp[j] = xp[j] > 0.0 ? xp[j] : 0.0;
    double acc[11];
    #pragma unroll
    for (int c = 0; c < 11; ++c) acc[c] = 0.0;
    #pragma unroll
    for (int j = 0; j < 4; ++j) {
        const float* wrow = Wc + (size_t)(lane * 4 + j) * 11;
        #pragma unroll
        for (int c = 0; c < 11; ++c) acc[c] += xp[j] * (double)wrow[c];
    }
    #pragma unroll
    for (int c = 0; c < 11; ++c) {
        double v = acc[c];
        #pragma unroll
        for (int o = 32; o > 0; o >>= 1) v += __shfl_down(v, o, 64);
        if (lane == 0) out[(size_t)r * 11 + c] = (float)(v + (double)bc[c]);
    }
}

// ---------------------------------------------------------------------------
// launch
// ---------------------------------------------------------------------------
extern "C" void kernel_launch(void* const* d_in, const int* in_sizes, int n_in,
                              void* d_out, int out_size, void* d_ws, size_t ws_size,
                              hipStream_t stream) {
    const float* f0  = (const float*)d_in[0];
    const float* f1  = (const float*)d_in[1];
    const int*   ei  = (const int*)d_in[2];
    const float* Wr  = (const float*)d_in[3];
    const float* Wn  = (const float*)d_in[4];
    const float* b   = (const float*)d_in[5];
    const float* Wpr = (const float*)d_in[6];
    const float* Wpn = (const float*)d_in[7];
    const float* bp  = (const float*)d_in[8];
    const float* Wc  = (const float*)d_in[9];
    const float* bc  = (const float*)d_in[10];
    float* out = (float*)d_out;

    const int N = in_sizes[0] / 128;   // 32768
    const int E = in_sizes[2] / 2;     // 524288
    const int K = (N + 1) / 2;         // 16384
    const int L = in_sizes[5] / 256;   // 3 layers

    const int* src = ei;
    const int* dst = ei + E;

    // workspace layout (256B aligned slices)
    char* p = (char*)d_ws;
    auto take = [&](size_t bytes) {
        char* r = p;
        p += (bytes + 255) & ~(size_t)255;
        return r;
    };
    float*  xA      = (float*)take((size_t)N * 256 * 4);
    float*  xB      = (float*)take((size_t)N * 256 * 4);
    float*  agg     = (float*)take((size_t)N * 256 * 4);
    int*    counts  = (int*)take((size_t)N * 4);
    int*    offs    = (int*)take((size_t)(N + 1) * 4);
    int*    csr     = (int*)take((size_t)E * 4);
    double* sc      = (double*)take((size_t)N * 8);
    unsigned long long* keys = (unsigned long long*)take((size_t)N * 8);
    int*    rankcnt = (int*)take((size_t)N * 4);
    double* topd    = (double*)take((size_t)K * 8);
    int*    perm    = (int*)take((size_t)K * 4);
    (void)ws_size;

    hipMemsetAsync(counts, 0, (size_t)N * 4, stream);
    hipMemsetAsync(rankcnt, 0, (size_t)N * 4, stream);

    concat_kernel<<<(N * 64 + 255) / 256, 256, 0, stream>>>(f0, f1, xA, N);
    count_kernel<<<(E + 255) / 256, 256, 0, stream>>>(dst, counts, E);
    scan_kernel<<<1, 1024, 0, stream>>>(counts, offs, N, E);
    fill_kernel<<<(E + 255) / 256, 256, 0, stream>>>(dst, offs, counts, csr, E);
    bsort_kernel<<<(N + 255) / 256, 256, 0, stream>>>(csr, offs, src, N);

    float* xcur = xA;
    float* xnext = xB;
    for (int i = 0; i < L; ++i) {
        segsum_kernel<<<N / 4, 256, 0, stream>>>(xcur, csr, offs, agg, N);
        gemm_two_kernel<<<dim3(256 / BN, N / BM), 256, 0, stream>>>(
            xcur, agg, Wr + (size_t)i * 65536, Wn + (size_t)i * 65536,
            b + (size_t)i * 256, xnext, N, 1);
        float* tmp = xcur; xcur = xnext; xnext = tmp;
    }
    // xcur == x3
    segsum_kernel<<<N / 4, 256, 0, stream>>>(xcur, csr, offs, agg, N);
    score_kernel<<<N / 4, 256, 0, stream>>>(xcur, agg, Wpr, Wpn, bp, sc, keys, N);
    rank_count_kernel<<<dim3(N / TJ, N / TI), 256, 0, stream>>>(keys, rankcnt, N);
    rank_scatter_kernel<<<(N + 255) / 256, 256, 0, stream>>>(rankcnt, sc, perm, topd, N, K);
    out_kernel<<<K / 4, 256, 0, stream>>>(xcur, perm, topd, Wc, bc, out, K);
}

// Round 3
// 882.777 us; speedup vs baseline: 2.1796x; 1.1327x over previous
//
#include <hip/hip_runtime.h>
#include <hip/hip_bf16.h>
#include <math.h>
#include <stdint.h>

// N = 32768 nodes, D = 256 features, E = 524288 edges, L = 3 layers,
// K = 16384 (top-k), C = 11 classes.

// ---------------------------------------------------------------------------
// 1. concat f0,f1 -> x0 [N][256]
// ---------------------------------------------------------------------------
__global__ __launch_bounds__(256) void concat_kernel(const float* __restrict__ f0,
                                                     const float* __restrict__ f1,
                                                     float* __restrict__ x,
                                                     int N) {
    int gid = blockIdx.x * blockDim.x + threadIdx.x;  // one float4 per thread
    int total = N * 64;                               // 64 float4 per row
    if (gid >= total) return;
    int n = gid >> 6;
    int q = gid & 63;
    float4 v;
    if (q < 32) v = *(const float4*)(f0 + (size_t)n * 128 + q * 4);
    else        v = *(const float4*)(f1 + (size_t)n * 128 + (q - 32) * 4);
    *(float4*)(x + (size_t)n * 256 + q * 4) = v;
}

// ---------------------------------------------------------------------------
// 2a. histogram of dst
// ---------------------------------------------------------------------------
__global__ __launch_bounds__(256) void count_kernel(const int* __restrict__ dst,
                                                    int* __restrict__ counts, int E) {
    int e = blockIdx.x * blockDim.x + threadIdx.x;
    if (e < E) atomicAdd(&counts[dst[e]], 1);
}

// ---------------------------------------------------------------------------
// 2b. exclusive scan of counts -> offsets[N+1]; zero counts (reused as cursor)
// ---------------------------------------------------------------------------
__global__ __launch_bounds__(1024) void scan_kernel(int* __restrict__ counts,
                                                    int* __restrict__ offs,
                                                    int N, int E) {
    __shared__ int s[1024];
    int t = threadIdx.x;
    int base = t * 32;
    int local[32];
    int sum = 0;
    #pragma unroll
    for (int j = 0; j < 32; ++j) { local[j] = counts[base + j]; sum += local[j]; }
    s[t] = sum;
    __syncthreads();
    for (int off = 1; off < 1024; off <<= 1) {
        int other = (t >= off) ? s[t - off] : 0;
        __syncthreads();
        s[t] += other;
        __syncthreads();
    }
    int run = s[t] - sum;  // exclusive base for this thread
    #pragma unroll
    for (int j = 0; j < 32; ++j) {
        offs[base + j] = run;
        run += local[j];
        counts[base + j] = 0;   // reset: reused as cursor in fill_kernel
    }
    if (t == 1023) offs[N] = E;
}

// ---------------------------------------------------------------------------
// 2c. scatter edge ids into CSR buckets
// ---------------------------------------------------------------------------
__global__ __launch_bounds__(256) void fill_kernel(const int* __restrict__ dst,
                                                   const int* __restrict__ offs,
                                                   int* __restrict__ cursor,
                                                   int* __restrict__ csr, int E) {
    int e = blockIdx.x * blockDim.x + threadIdx.x;
    if (e >= E) return;
    int d = dst[e];
    int pos = offs[d] + atomicAdd(&cursor[d], 1);
    csr[pos] = e;
}

// ---------------------------------------------------------------------------
// 2d. per-bucket insertion sort by edge id (deterministic), map edge->src
// ---------------------------------------------------------------------------
__global__ __launch_bounds__(256) void bsort_kernel(int* __restrict__ csr,
                                                    const int* __restrict__ offs,
                                                    const int* __restrict__ src,
                                                    int N) {
    int i = blockIdx.x * blockDim.x + threadIdx.x;
    if (i >= N) return;
    int beg = offs[i], end = offs[i + 1];
    for (int a = beg + 1; a < end; ++a) {
        int v = csr[a];
        int b = a - 1;
        while (b >= beg && csr[b] > v) { csr[b + 1] = csr[b]; --b; }
        csr[b + 1] = v;
    }
    for (int p = beg; p < end; ++p) csr[p] = src[csr[p]];
}

// ---------------------------------------------------------------------------
// 3. segment sum: agg[n][:] = sum over csr bucket of x[src][:]
// ---------------------------------------------------------------------------
__global__ __launch_bounds__(256) void segsum_kernel(const float* __restrict__ X,
                                                     const int* __restrict__ csr,
                                                     const int* __restrict__ offs,
                                                     float* __restrict__ AGG, int N) {
    int w = threadIdx.x >> 6;
    int lane = threadIdx.x & 63;
    int n = blockIdx.x * 4 + w;
    if (n >= N) return;
    int beg = offs[n], end = offs[n + 1];
    float4 acc = make_float4(0.f, 0.f, 0.f, 0.f);
    for (int p = beg; p < end; ++p) {
        int s = csr[p];
        float4 v = *(const float4*)(X + (size_t)s * 256 + lane * 4);
        acc.x += v.x; acc.y += v.y; acc.z += v.z; acc.w += v.w;
    }
    *(float4*)(AGG + (size_t)n * 256 + lane * 4) = acc;
}

// ---------------------------------------------------------------------------
// 4. fused GEMM: Y = relu(X @ W1 + G @ W2 + bias)   [N,512-split] x [512,256]
//    128x128 tile, BK=16, 256 threads, 8x8 micro-tile per thread.
// ---------------------------------------------------------------------------
#define GBM 128
#define GBN 128
#define GBK 16
__global__ __launch_bounds__(256) void gemm_two_kernel(const float* __restrict__ X,
                                                       const float* __restrict__ G,
                                                       const float* __restrict__ W1,
                                                       const float* __restrict__ W2,
                                                       const float* __restrict__ bias,
                                                       float* __restrict__ Y,
                                                       int N) {
    __shared__ float As[GBK][GBM + 4];
    __shared__ float Ws[GBK][GBN + 4];
    const int tid = threadIdx.x;
    const int tcol = tid & 15;          // 0..15 -> 8 output cols
    const int trow = tid >> 4;          // 0..15 -> 8 output rows
    const int rowBase = blockIdx.y * GBM;
    const int colBase = blockIdx.x * GBN;

    const int ar0 = tid >> 2;           // A stage row (0..63), +64 for 2nd
    const int ak  = (tid & 3) * 4;      // A stage k offset (float4)
    const int wk0 = tid >> 5;           // W stage k row (0..7), +8 for 2nd
    const int wc  = (tid & 31) * 4;     // W stage col offset (float4)

    float acc[8][8];
    #pragma unroll
    for (int i = 0; i < 8; ++i)
        #pragma unroll
        for (int j = 0; j < 8; ++j) acc[i][j] = 0.f;

    for (int kt = 0; kt < 32; ++kt) {
        const int kb = kt * GBK;
        const float* Asrc = (kb < 256) ? X : G;
        const float* Wsrc = (kb < 256) ? W1 : W2;
        const int kloc = kb & 255;
        float4 a0 = *(const float4*)(Asrc + (size_t)(rowBase + ar0) * 256 + kloc + ak);
        float4 a1 = *(const float4*)(Asrc + (size_t)(rowBase + ar0 + 64) * 256 + kloc + ak);
        float4 w0 = *(const float4*)(Wsrc + (size_t)(kloc + wk0) * 256 + colBase + wc);
        float4 w1 = *(const float4*)(Wsrc + (size_t)(kloc + wk0 + 8) * 256 + colBase + wc);
        __syncthreads();   // previous tile fully consumed
        As[ak + 0][ar0] = a0.x; As[ak + 1][ar0] = a0.y;
        As[ak + 2][ar0] = a0.z; As[ak + 3][ar0] = a0.w;
        As[ak + 0][ar0 + 64] = a1.x; As[ak + 1][ar0 + 64] = a1.y;
        As[ak + 2][ar0 + 64] = a1.z; As[ak + 3][ar0 + 64] = a1.w;
        *(float4*)&Ws[wk0][wc] = w0;
        *(float4*)&Ws[wk0 + 8][wc] = w1;
        __syncthreads();
        #pragma unroll
        for (int kk = 0; kk < GBK; ++kk) {
            float a[8], w[8];
            *(float4*)&a[0] = *(const float4*)&As[kk][trow * 8];
            *(float4*)&a[4] = *(const float4*)&As[kk][trow * 8 + 4];
            *(float4*)&w[0] = *(const float4*)&Ws[kk][tcol * 8];
            *(float4*)&w[4] = *(const float4*)&Ws[kk][tcol * 8 + 4];
            #pragma unroll
            for (int i = 0; i < 8; ++i)
                #pragma unroll
                for (int j = 0; j < 8; ++j)
                    acc[i][j] = fmaf(a[i], w[j], acc[i][j]);
        }
    }
    #pragma unroll
    for (int i = 0; i < 8; ++i) {
        const int row = rowBase + trow * 8 + i;
        float o[8];
        #pragma unroll
        for (int j = 0; j < 8; ++j) {
            float v = acc[i][j] + bias[colBase + tcol * 8 + j];
            o[j] = fmaxf(v, 0.f);
        }
        *(float4*)(Y + (size_t)row * 256 + colBase + tcol * 8)     = *(const float4*)&o[0];
        *(float4*)(Y + (size_t)row * 256 + colBase + tcol * 8 + 4) = *(const float4*)&o[4];
    }
}

// ---------------------------------------------------------------------------
// 5a. per-node dots: yr[n] = x3[n].Wpr, yn[n] = x3[n].Wpn   (f64)
// ---------------------------------------------------------------------------
__global__ __launch_bounds__(256) void dot_kernel(const float* __restrict__ X3,
                                                  const float* __restrict__ Wpr,
                                                  const float* __restrict__ Wpn,
                                                  double* __restrict__ yr,
                                                  double* __restrict__ yn, int N) {
    int w = threadIdx.x >> 6;
    int lane = threadIdx.x & 63;
    int n = blockIdx.x * 4 + w;
    if (n >= N) return;
    float4 xv = *(const float4*)(X3 + (size_t)n * 256 + lane * 4);
    float4 wr = *(const float4*)(Wpr + lane * 4);
    float4 wn = *(const float4*)(Wpn + lane * 4);
    double dr = (double)xv.x * wr.x + (double)xv.y * wr.y +
                (double)xv.z * wr.z + (double)xv.w * wr.w;
    double dn = (double)xv.x * wn.x + (double)xv.y * wn.y +
                (double)xv.z * wn.z + (double)xv.w * wn.w;
    #pragma unroll
    for (int o = 32; o > 0; o >>= 1) {
        dr += __shfl_down(dr, o, 64);
        dn += __shfl_down(dn, o, 64);
    }
    if (lane == 0) { yr[n] = dr; yn[n] = dn; }
}

// ---------------------------------------------------------------------------
// 5b. score[n] = yr[n] + sum_{bucket} yn[src] + bp; emit order-preserving key
// ---------------------------------------------------------------------------
__global__ __launch_bounds__(256) void score_gather_kernel(
        const double* __restrict__ yr, const double* __restrict__ yn,
        const int* __restrict__ csr, const int* __restrict__ offs,
        const float* __restrict__ bp,
        double* __restrict__ sc, unsigned long long* __restrict__ keys, int N) {
    int n = blockIdx.x * blockDim.x + threadIdx.x;
    if (n >= N) return;
    double s = yr[n] + (double)bp[0];
    int beg = offs[n], end = offs[n + 1];
    for (int p = beg; p < end; ++p) s += yn[csr[p]];
    sc[n] = s;
    long long sb = __double_as_longlong(s);
    keys[n] = (sb < 0) ? ~(unsigned long long)sb
                       : ((unsigned long long)sb | 0x8000000000000000ULL);
}

// ---------------------------------------------------------------------------
// 6a. tiled exact rank-count on uint64 keys.
//     8 i-keys per thread in VGPRs, j streamed through LDS as b128 chunks.
// ---------------------------------------------------------------------------
#define RTI 2048
#define RTJ 1024
__global__ __launch_bounds__(256) void rank_count_kernel(
        const unsigned long long* __restrict__ keys,
        int* __restrict__ rankcnt, int N) {
    __shared__ __align__(16) unsigned long long sk[RTJ];
    const int tid = threadIdx.x;
    const int ibase = blockIdx.y * RTI;
    const int jbase = blockIdx.x * RTJ;

    unsigned long long ki[8];
    #pragma unroll
    for (int r = 0; r < 8; ++r) ki[r] = keys[ibase + r * 256 + tid];
    for (int t = tid; t < RTJ; t += 256) sk[t] = keys[jbase + t];
    __syncthreads();

    int cnt[8] = {0, 0, 0, 0, 0, 0, 0, 0};
    if (jbase + RTJ <= ibase) {
        // all j < i : tie counts -> kj >= ki
        for (int u = 0; u < RTJ; u += 8) {
            ulonglong2 p0 = *(const ulonglong2*)&sk[u];
            ulonglong2 p1 = *(const ulonglong2*)&sk[u + 2];
            ulonglong2 p2 = *(const ulonglong2*)&sk[u + 4];
            ulonglong2 p3 = *(const ulonglong2*)&sk[u + 6];
            #pragma unroll
            for (int r = 0; r < 8; ++r) {
                cnt[r] += (int)(p0.x >= ki[r]) + (int)(p0.y >= ki[r])
                        + (int)(p1.x >= ki[r]) + (int)(p1.y >= ki[r])
                        + (int)(p2.x >= ki[r]) + (int)(p2.y >= ki[r])
                        + (int)(p3.x >= ki[r]) + (int)(p3.y >= ki[r]);
            }
        }
    } else if (jbase >= ibase + RTI) {
        // all j > i : tie doesn't count -> kj > ki
        for (int u = 0; u < RTJ; u += 8) {
            ulonglong2 p0 = *(const ulonglong2*)&sk[u];
            ulonglong2 p1 = *(const ulonglong2*)&sk[u + 2];
            ulonglong2 p2 = *(const ulonglong2*)&sk[u + 4];
            ulonglong2 p3 = *(const ulonglong2*)&sk[u + 6];
            #pragma unroll
            for (int r = 0; r < 8; ++r) {
                cnt[r] += (int)(p0.x > ki[r]) + (int)(p0.y > ki[r])
                        + (int)(p1.x > ki[r]) + (int)(p1.y > ki[r])
                        + (int)(p2.x > ki[r]) + (int)(p2.y > ki[r])
                        + (int)(p3.x > ki[r]) + (int)(p3.y > ki[r]);
            }
        }
    } else {
        // diagonal tile: full three-term compare (u < thr[r]  <=>  j < i)
        int thr[8];
        #pragma unroll
        for (int r = 0; r < 8; ++r) thr[r] = ibase + r * 256 + tid - jbase;
        for (int u = 0; u < RTJ; ++u) {
            unsigned long long kj = sk[u];
            #pragma unroll
            for (int r = 0; r < 8; ++r)
                cnt[r] += (kj > ki[r]) || (kj == ki[r] && u < thr[r]);
        }
    }
    #pragma unroll
    for (int r = 0; r < 8; ++r)
        atomicAdd(&rankcnt[ibase + r * 256 + tid], cnt[r]);
}

// ---------------------------------------------------------------------------
// 6b. scatter by rank
// ---------------------------------------------------------------------------
__global__ __launch_bounds__(256) void rank_scatter_kernel(
        const int* __restrict__ rankcnt,
        const double* __restrict__ sc,
        int* __restrict__ perm,
        double* __restrict__ topd, int N, int K) {
    int i = blockIdx.x * blockDim.x + threadIdx.x;
    if (i >= N) return;
    int rank = rankcnt[i];
    if (rank < K) { perm[rank] = i; topd[rank] = sc[i]; }
}

// ---------------------------------------------------------------------------
// 7. head: out[r] = relu(x3[perm[r]] * tanh(score_r)) @ Wc + bc  (f64 accum)
// ---------------------------------------------------------------------------
__global__ __launch_bounds__(256) void out_kernel(const float* __restrict__ X3,
                                                  const int* __restrict__ perm,
                                                  const double* __restrict__ topd,
                                                  const float* __restrict__ Wc,
                                                  const float* __restrict__ bc,
                                                  float* __restrict__ out, int K) {
    int w = threadIdx.x >> 6;
    int lane = threadIdx.x & 63;
    int r = blockIdx.x * 4 + w;
    if (r >= K) return;
    int p = perm[r];
    double t = tanh(topd[r]);
    float4 xv = *(const float4*)(X3 + (size_t)p * 256 + lane * 4);
    double xp[4];
    xp[0] = (double)xv.x * t; xp[1] = (double)xv.y * t;
    xp[2] = (double)xv.z * t; xp[3] = (double)xv.w * t;
    #pragma unroll
    for (int j = 0; j < 4; ++j) xp[j] = xp[j] > 0.0 ? xp[j] : 0.0;
    double acc[11];
    #pragma unroll
    for (int c = 0; c < 11; ++c) acc[c] = 0.0;
    #pragma unroll
    for (int j = 0; j < 4; ++j) {
        const float* wrow = Wc + (size_t)(lane * 4 + j) * 11;
        #pragma unroll
        for (int c = 0; c < 11; ++c) acc[c] += xp[j] * (double)wrow[c];
    }
    #pragma unroll
    for (int c = 0; c < 11; ++c) {
        double v = acc[c];
        #pragma unroll
        for (int o = 32; o > 0; o >>= 1) v += __shfl_down(v, o, 64);
        if (lane == 0) out[(size_t)r * 11 + c] = (float)(v + (double)bc[c]);
    }
}

// ---------------------------------------------------------------------------
// launch
// ---------------------------------------------------------------------------
extern "C" void kernel_launch(void* const* d_in, const int* in_sizes, int n_in,
                              void* d_out, int out_size, void* d_ws, size_t ws_size,
                              hipStream_t stream) {
    const float* f0  = (const float*)d_in[0];
    const float* f1  = (const float*)d_in[1];
    const int*   ei  = (const int*)d_in[2];
    const float* Wr  = (const float*)d_in[3];
    const float* Wn  = (const float*)d_in[4];
    const float* b   = (const float*)d_in[5];
    const float* Wpr = (const float*)d_in[6];
    const float* Wpn = (const float*)d_in[7];
    const float* bp  = (const float*)d_in[8];
    const float* Wc  = (const float*)d_in[9];
    const float* bc  = (const float*)d_in[10];
    float* out = (float*)d_out;

    const int N = in_sizes[0] / 128;   // 32768
    const int E = in_sizes[2] / 2;     // 524288
    const int K = (N + 1) / 2;         // 16384
    const int L = in_sizes[5] / 256;   // 3 layers

    const int* src = ei;
    const int* dst = ei + E;

    // workspace layout (256B aligned slices)
    char* p = (char*)d_ws;
    auto take = [&](size_t bytes) {
        char* r = p;
        p += (bytes + 255) & ~(size_t)255;
        return r;
    };
    float*  xA      = (float*)take((size_t)N * 256 * 4);
    float*  xB      = (float*)take((size_t)N * 256 * 4);
    float*  agg     = (float*)take((size_t)N * 256 * 4);
    int*    counts  = (int*)take((size_t)N * 4);
    int*    offs    = (int*)take((size_t)(N + 1) * 4);
    int*    csr     = (int*)take((size_t)E * 4);
    double* sc      = (double*)take((size_t)N * 8);
    unsigned long long* keys = (unsigned long long*)take((size_t)N * 8);
    int*    rankcnt = (int*)take((size_t)N * 4);
    double* topd    = (double*)take((size_t)K * 8);
    int*    perm    = (int*)take((size_t)K * 4);
    double* yrv     = (double*)take((size_t)N * 8);
    double* ynv     = (double*)take((size_t)N * 8);
    (void)ws_size;

    hipMemsetAsync(counts, 0, (size_t)N * 4, stream);
    hipMemsetAsync(rankcnt, 0, (size_t)N * 4, stream);

    concat_kernel<<<(N * 64 + 255) / 256, 256, 0, stream>>>(f0, f1, xA, N);
    count_kernel<<<(E + 255) / 256, 256, 0, stream>>>(dst, counts, E);
    scan_kernel<<<1, 1024, 0, stream>>>(counts, offs, N, E);
    fill_kernel<<<(E + 255) / 256, 256, 0, stream>>>(dst, offs, counts, csr, E);
    bsort_kernel<<<(N + 255) / 256, 256, 0, stream>>>(csr, offs, src, N);

    float* xcur = xA;
    float* xnext = xB;
    for (int i = 0; i < L; ++i) {
        segsum_kernel<<<N / 4, 256, 0, stream>>>(xcur, csr, offs, agg, N);
        gemm_two_kernel<<<dim3(256 / GBN, N / GBM), 256, 0, stream>>>(
            xcur, agg, Wr + (size_t)i * 65536, Wn + (size_t)i * 65536,
            b + (size_t)i * 256, xnext, N);
        float* tmp = xcur; xcur = xnext; xnext = tmp;
    }
    // xcur == x3
    dot_kernel<<<N / 4, 256, 0, stream>>>(xcur, Wpr, Wpn, yrv, ynv, N);
    score_gather_kernel<<<N / 256, 256, 0, stream>>>(yrv, ynv, csr, offs, bp, sc, keys, N);
    rank_count_kernel<<<dim3(N / RTJ, N / RTI), 256, 0, stream>>>(keys, rankcnt, N);
    rank_scatter_kernel<<<(N + 255) / 256, 256, 0, stream>>>(rankcnt, sc, perm, topd, N, K);
    out_kernel<<<K / 4, 256, 0, stream>>>(xcur, perm, topd, Wc, bc, out, K);
}

// Round 4
// 817.138 us; speedup vs baseline: 2.3547x; 1.0803x over previous
//
#include <hip/hip_runtime.h>
#include <hip/hip_bf16.h>
#include <math.h>
#include <stdint.h>

// N = 32768 nodes, D = 256 features, E = 524288 edges, L = 3 layers,
// K = 16384 (top-k), C = 11 classes.

// ---------------------------------------------------------------------------
// 1. concat f0,f1 -> x0 [N][256]
// ---------------------------------------------------------------------------
__global__ __launch_bounds__(256) void concat_kernel(const float* __restrict__ f0,
                                                     const float* __restrict__ f1,
                                                     float* __restrict__ x,
                                                     int N) {
    int gid = blockIdx.x * blockDim.x + threadIdx.x;  // one float4 per thread
    int total = N * 64;                               // 64 float4 per row
    if (gid >= total) return;
    int n = gid >> 6;
    int q = gid & 63;
    float4 v;
    if (q < 32) v = *(const float4*)(f0 + (size_t)n * 128 + q * 4);
    else        v = *(const float4*)(f1 + (size_t)n * 128 + (q - 32) * 4);
    *(float4*)(x + (size_t)n * 256 + q * 4) = v;
}

// ---------------------------------------------------------------------------
// 2a. histogram of dst
// ---------------------------------------------------------------------------
__global__ __launch_bounds__(256) void count_kernel(const int* __restrict__ dst,
                                                    int* __restrict__ counts, int E) {
    int e = blockIdx.x * blockDim.x + threadIdx.x;
    if (e < E) atomicAdd(&counts[dst[e]], 1);
}

// ---------------------------------------------------------------------------
// 2b. exclusive scan of counts -> offsets[N+1]; zero counts (reused as cursor)
// ---------------------------------------------------------------------------
__global__ __launch_bounds__(1024) void scan_kernel(int* __restrict__ counts,
                                                    int* __restrict__ offs,
                                                    int N, int E) {
    __shared__ int s[1024];
    int t = threadIdx.x;
    int base = t * 32;
    int local[32];
    int sum = 0;
    #pragma unroll
    for (int j = 0; j < 32; ++j) { local[j] = counts[base + j]; sum += local[j]; }
    s[t] = sum;
    __syncthreads();
    for (int off = 1; off < 1024; off <<= 1) {
        int other = (t >= off) ? s[t - off] : 0;
        __syncthreads();
        s[t] += other;
        __syncthreads();
    }
    int run = s[t] - sum;  // exclusive base for this thread
    #pragma unroll
    for (int j = 0; j < 32; ++j) {
        offs[base + j] = run;
        run += local[j];
        counts[base + j] = 0;   // reset: reused as cursor in fill_kernel
    }
    if (t == 1023) offs[N] = E;
}

// ---------------------------------------------------------------------------
// 2c. scatter edge ids into CSR buckets
// ---------------------------------------------------------------------------
__global__ __launch_bounds__(256) void fill_kernel(const int* __restrict__ dst,
                                                   const int* __restrict__ offs,
                                                   int* __restrict__ cursor,
                                                   int* __restrict__ csr, int E) {
    int e = blockIdx.x * blockDim.x + threadIdx.x;
    if (e >= E) return;
    int d = dst[e];
    int pos = offs[d] + atomicAdd(&cursor[d], 1);
    csr[pos] = e;
}

// ---------------------------------------------------------------------------
// 2d. per-bucket insertion sort by edge id (deterministic), map edge->src
// ---------------------------------------------------------------------------
__global__ __launch_bounds__(256) void bsort_kernel(int* __restrict__ csr,
                                                    const int* __restrict__ offs,
                                                    const int* __restrict__ src,
                                                    int N) {
    int i = blockIdx.x * blockDim.x + threadIdx.x;
    if (i >= N) return;
    int beg = offs[i], end = offs[i + 1];
    for (int a = beg + 1; a < end; ++a) {
        int v = csr[a];
        int b = a - 1;
        while (b >= beg && csr[b] > v) { csr[b + 1] = csr[b]; --b; }
        csr[b + 1] = v;
    }
    for (int p = beg; p < end; ++p) csr[p] = src[csr[p]];
}

// ---------------------------------------------------------------------------
// 3. segment sum: agg[n][:] = sum over csr bucket of x[src][:]
// ---------------------------------------------------------------------------
__global__ __launch_bounds__(256) void segsum_kernel(const float* __restrict__ X,
                                                     const int* __restrict__ csr,
                                                     const int* __restrict__ offs,
                                                     float* __restrict__ AGG, int N) {
    int w = threadIdx.x >> 6;
    int lane = threadIdx.x & 63;
    int n = blockIdx.x * 4 + w;
    if (n >= N) return;
    int beg = offs[n], end = offs[n + 1];
    float4 acc = make_float4(0.f, 0.f, 0.f, 0.f);
    for (int p = beg; p < end; ++p) {
        int s = csr[p];
        float4 v = *(const float4*)(X + (size_t)s * 256 + lane * 4);
        acc.x += v.x; acc.y += v.y; acc.z += v.z; acc.w += v.w;
    }
    *(float4*)(AGG + (size_t)n * 256 + lane * 4) = acc;
}

// ---------------------------------------------------------------------------
// 4. fused GEMM: Y = relu(X @ W1 + G @ W2 + bias)   [N,512-split] x [512,256]
//    128x128 tile, BK=16, 256 threads, 8x8 micro-tile per thread.
// ---------------------------------------------------------------------------
#define GBM 128
#define GBN 128
#define GBK 16
__global__ __launch_bounds__(256) void gemm_two_kernel(const float* __restrict__ X,
                                                       const float* __restrict__ G,
                                                       const float* __restrict__ W1,
                                                       const float* __restrict__ W2,
                                                       const float* __restrict__ bias,
                                                       float* __restrict__ Y,
                                                       int N) {
    __shared__ float As[GBK][GBM + 4];
    __shared__ float Ws[GBK][GBN + 4];
    const int tid = threadIdx.x;
    const int tcol = tid & 15;          // 0..15 -> 8 output cols
    const int trow = tid >> 4;          // 0..15 -> 8 output rows
    const int rowBase = blockIdx.y * GBM;
    const int colBase = blockIdx.x * GBN;

    const int ar0 = tid >> 2;           // A stage row (0..63), +64 for 2nd
    const int ak  = (tid & 3) * 4;      // A stage k offset (float4)
    const int wk0 = tid >> 5;           // W stage k row (0..7), +8 for 2nd
    const int wc  = (tid & 31) * 4;     // W stage col offset (float4)

    float acc[8][8];
    #pragma unroll
    for (int i = 0; i < 8; ++i)
        #pragma unroll
        for (int j = 0; j < 8; ++j) acc[i][j] = 0.f;

    for (int kt = 0; kt < 32; ++kt) {
        const int kb = kt * GBK;
        const float* Asrc = (kb < 256) ? X : G;
        const float* Wsrc = (kb < 256) ? W1 : W2;
        const int kloc = kb & 255;
        float4 a0 = *(const float4*)(Asrc + (size_t)(rowBase + ar0) * 256 + kloc + ak);
        float4 a1 = *(const float4*)(Asrc + (size_t)(rowBase + ar0 + 64) * 256 + kloc + ak);
        float4 w0 = *(const float4*)(Wsrc + (size_t)(kloc + wk0) * 256 + colBase + wc);
        float4 w1 = *(const float4*)(Wsrc + (size_t)(kloc + wk0 + 8) * 256 + colBase + wc);
        __syncthreads();   // previous tile fully consumed
        As[ak + 0][ar0] = a0.x; As[ak + 1][ar0] = a0.y;
        As[ak + 2][ar0] = a0.z; As[ak + 3][ar0] = a0.w;
        As[ak + 0][ar0 + 64] = a1.x; As[ak + 1][ar0 + 64] = a1.y;
        As[ak + 2][ar0 + 64] = a1.z; As[ak + 3][ar0 + 64] = a1.w;
        *(float4*)&Ws[wk0][wc] = w0;
        *(float4*)&Ws[wk0 + 8][wc] = w1;
        __syncthreads();
        #pragma unroll
        for (int kk = 0; kk < GBK; ++kk) {
            float a[8], w[8];
            *(float4*)&a[0] = *(const float4*)&As[kk][trow * 8];
            *(float4*)&a[4] = *(const float4*)&As[kk][trow * 8 + 4];
            *(float4*)&w[0] = *(const float4*)&Ws[kk][tcol * 8];
            *(float4*)&w[4] = *(const float4*)&Ws[kk][tcol * 8 + 4];
            #pragma unroll
            for (int i = 0; i < 8; ++i)
                #pragma unroll
                for (int j = 0; j < 8; ++j)
                    acc[i][j] = fmaf(a[i], w[j], acc[i][j]);
        }
    }
    #pragma unroll
    for (int i = 0; i < 8; ++i) {
        const int row = rowBase + trow * 8 + i;
        float o[8];
        #pragma unroll
        for (int j = 0; j < 8; ++j) {
            float v = acc[i][j] + bias[colBase + tcol * 8 + j];
            o[j] = fmaxf(v, 0.f);
        }
        *(float4*)(Y + (size_t)row * 256 + colBase + tcol * 8)     = *(const float4*)&o[0];
        *(float4*)(Y + (size_t)row * 256 + colBase + tcol * 8 + 4) = *(const float4*)&o[4];
    }
}

// ---------------------------------------------------------------------------
// 5a. per-node dots: yr[n] = x3[n].Wpr, yn[n] = x3[n].Wpn   (f64)
// ---------------------------------------------------------------------------
__global__ __launch_bounds__(256) void dot_kernel(const float* __restrict__ X3,
                                                  const float* __restrict__ Wpr,
                                                  const float* __restrict__ Wpn,
                                                  double* __restrict__ yr,
                                                  double* __restrict__ yn, int N) {
    int w = threadIdx.x >> 6;
    int lane = threadIdx.x & 63;
    int n = blockIdx.x * 4 + w;
    if (n >= N) return;
    float4 xv = *(const float4*)(X3 + (size_t)n * 256 + lane * 4);
    float4 wr = *(const float4*)(Wpr + lane * 4);
    float4 wn = *(const float4*)(Wpn + lane * 4);
    double dr = (double)xv.x * wr.x + (double)xv.y * wr.y +
                (double)xv.z * wr.z + (double)xv.w * wr.w;
    double dn = (double)xv.x * wn.x + (double)xv.y * wn.y +
                (double)xv.z * wn.z + (double)xv.w * wn.w;
    #pragma unroll
    for (int o = 32; o > 0; o >>= 1) {
        dr += __shfl_down(dr, o, 64);
        dn += __shfl_down(dn, o, 64);
    }
    if (lane == 0) { yr[n] = dr; yn[n] = dn; }
}

// ---------------------------------------------------------------------------
// 5b. score[n] = yr[n] + sum_{bucket} yn[src] + bp; emit order-preserving key
// ---------------------------------------------------------------------------
__global__ __launch_bounds__(256) void score_gather_kernel(
        const double* __restrict__ yr, const double* __restrict__ yn,
        const int* __restrict__ csr, const int* __restrict__ offs,
        const float* __restrict__ bp,
        double* __restrict__ sc, unsigned long long* __restrict__ keys, int N) {
    int n = blockIdx.x * blockDim.x + threadIdx.x;
    if (n >= N) return;
    double s = yr[n] + (double)bp[0];
    int beg = offs[n], end = offs[n + 1];
    for (int p = beg; p < end; ++p) s += yn[csr[p]];
    sc[n] = s;
    long long sb = __double_as_longlong(s);
    keys[n] = (sb < 0) ? ~(unsigned long long)sb
                       : ((unsigned long long)sb | 0x8000000000000000ULL);
}

// ---------------------------------------------------------------------------
// 6a. tiled exact rank-count on uint64 keys.
//     RTI=1024 i (4 regs/thread) x RTJ=512 j (LDS) -> 2048 blocks (8/CU).
// ---------------------------------------------------------------------------
#define RTI 1024
#define RTJ 512
__global__ __launch_bounds__(256) void rank_count_kernel(
        const unsigned long long* __restrict__ keys,
        int* __restrict__ rankcnt, int N) {
    __shared__ __align__(16) unsigned long long sk[RTJ];
    const int tid = threadIdx.x;
    const int ibase = blockIdx.y * RTI;
    const int jbase = blockIdx.x * RTJ;

    unsigned long long ki[4];
    #pragma unroll
    for (int r = 0; r < 4; ++r) ki[r] = keys[ibase + r * 256 + tid];
    for (int t = tid; t < RTJ; t += 256) sk[t] = keys[jbase + t];
    __syncthreads();

    int cnt[4] = {0, 0, 0, 0};
    if (jbase + RTJ <= ibase) {
        // all j < i : tie counts -> kj >= ki
        for (int u = 0; u < RTJ; u += 8) {
            ulonglong2 p0 = *(const ulonglong2*)&sk[u];
            ulonglong2 p1 = *(const ulonglong2*)&sk[u + 2];
            ulonglong2 p2 = *(const ulonglong2*)&sk[u + 4];
            ulonglong2 p3 = *(const ulonglong2*)&sk[u + 6];
            #pragma unroll
            for (int r = 0; r < 4; ++r) {
                cnt[r] += (int)(p0.x >= ki[r]) + (int)(p0.y >= ki[r])
                        + (int)(p1.x >= ki[r]) + (int)(p1.y >= ki[r])
                        + (int)(p2.x >= ki[r]) + (int)(p2.y >= ki[r])
                        + (int)(p3.x >= ki[r]) + (int)(p3.y >= ki[r]);
            }
        }
    } else if (jbase >= ibase + RTI) {
        // all j > i : tie doesn't count -> kj > ki
        for (int u = 0; u < RTJ; u += 8) {
            ulonglong2 p0 = *(const ulonglong2*)&sk[u];
            ulonglong2 p1 = *(const ulonglong2*)&sk[u + 2];
            ulonglong2 p2 = *(const ulonglong2*)&sk[u + 4];
            ulonglong2 p3 = *(const ulonglong2*)&sk[u + 6];
            #pragma unroll
            for (int r = 0; r < 4; ++r) {
                cnt[r] += (int)(p0.x > ki[r]) + (int)(p0.y > ki[r])
                        + (int)(p1.x > ki[r]) + (int)(p1.y > ki[r])
                        + (int)(p2.x > ki[r]) + (int)(p2.y > ki[r])
                        + (int)(p3.x > ki[r]) + (int)(p3.y > ki[r]);
            }
        }
    } else {
        // diagonal tile: full three-term compare (u < thr[r]  <=>  j < i)
        int thr[4];
        #pragma unroll
        for (int r = 0; r < 4; ++r) thr[r] = ibase + r * 256 + tid - jbase;
        for (int u = 0; u < RTJ; ++u) {
            unsigned long long kj = sk[u];
            #pragma unroll
            for (int r = 0; r < 4; ++r)
                cnt[r] += (kj > ki[r]) || (kj == ki[r] && u < thr[r]);
        }
    }
    #pragma unroll
    for (int r = 0; r < 4; ++r)
        atomicAdd(&rankcnt[ibase + r * 256 + tid], cnt[r]);
}

// ---------------------------------------------------------------------------
// 6b. scatter by rank
// ---------------------------------------------------------------------------
__global__ __launch_bounds__(256) void rank_scatter_kernel(
        const int* __restrict__ rankcnt,
        const double* __restrict__ sc,
        int* __restrict__ perm,
        double* __restrict__ topd, int N, int K) {
    int i = blockIdx.x * blockDim.x + threadIdx.x;
    if (i >= N) return;
    int rank = rankcnt[i];
    if (rank < K) { perm[rank] = i; topd[rank] = sc[i]; }
}

// ---------------------------------------------------------------------------
// 7. head: out[r] = relu(x3[perm[r]] * tanh(score_r)) @ Wc + bc  (f64 accum)
// ---------------------------------------------------------------------------
__global__ __launch_bounds__(256) void out_kernel(const float* __restrict__ X3,
                                                  const int* __restrict__ perm,
                                                  const double* __restrict__ topd,
                                                  const float* __restrict__ Wc,
                                                  const float* __restrict__ bc,
                                                  float* __restrict__ out, int K) {
    int w = threadIdx.x >> 6;
    int lane = threadIdx.x & 63;
    int r = blockIdx.x * 4 + w;
    if (r >= K) return;
    int p = perm[r];
    double t = tanh(topd[r]);
    float4 xv = *(const float4*)(X3 + (size_t)p * 256 + lane * 4);
    double xp[4];
    xp[0] = (double)xv.x * t; xp[1] = (double)xv.y * t;
    xp[2] = (double)xv.z * t; xp[3] = (double)xv.w * t;
    #pragma unroll
    for (int j = 0; j < 4; ++j) xp[j] = xp[j] > 0.0 ? xp[j] : 0.0;
    double acc[11];
    #pragma unroll
    for (int c = 0; c < 11; ++c) acc[c] = 0.0;
    #pragma unroll
    for (int j = 0; j < 4; ++j) {
        const float* wrow = Wc + (size_t)(lane * 4 + j) * 11;
        #pragma unroll
        for (int c = 0; c < 11; ++c) acc[c] += xp[j] * (double)wrow[c];
    }
    #pragma unroll
    for (int c = 0; c < 11; ++c) {
        double v = acc[c];
        #pragma unroll
        for (int o = 32; o > 0; o >>= 1) v += __shfl_down(v, o, 64);
        if (lane == 0) out[(size_t)r * 11 + c] = (float)(v + (double)bc[c]);
    }
}

// ---------------------------------------------------------------------------
// launch
// ---------------------------------------------------------------------------
extern "C" void kernel_launch(void* const* d_in, const int* in_sizes, int n_in,
                              void* d_out, int out_size, void* d_ws, size_t ws_size,
                              hipStream_t stream) {
    const float* f0  = (const float*)d_in[0];
    const float* f1  = (const float*)d_in[1];
    const int*   ei  = (const int*)d_in[2];
    const float* Wr  = (const float*)d_in[3];
    const float* Wn  = (const float*)d_in[4];
    const float* b   = (const float*)d_in[5];
    const float* Wpr = (const float*)d_in[6];
    const float* Wpn = (const float*)d_in[7];
    const float* bp  = (const float*)d_in[8];
    const float* Wc  = (const float*)d_in[9];
    const float* bc  = (const float*)d_in[10];
    float* out = (float*)d_out;

    const int N = in_sizes[0] / 128;   // 32768
    const int E = in_sizes[2] / 2;     // 524288
    const int K = (N + 1) / 2;         // 16384
    const int L = in_sizes[5] / 256;   // 3 layers

    const int* src = ei;
    const int* dst = ei + E;

    // workspace layout (256B aligned slices)
    char* p = (char*)d_ws;
    auto take = [&](size_t bytes) {
        char* r = p;
        p += (bytes + 255) & ~(size_t)255;
        return r;
    };
    float*  xA      = (float*)take((size_t)N * 256 * 4);
    float*  xB      = (float*)take((size_t)N * 256 * 4);
    float*  agg     = (float*)take((size_t)N * 256 * 4);
    int*    counts  = (int*)take((size_t)N * 4);
    int*    offs    = (int*)take((size_t)(N + 1) * 4);
    int*    csr     = (int*)take((size_t)E * 4);
    double* sc      = (double*)take((size_t)N * 8);
    unsigned long long* keys = (unsigned long long*)take((size_t)N * 8);
    int*    rankcnt = (int*)take((size_t)N * 4);
    double* topd    = (double*)take((size_t)K * 8);
    int*    perm    = (int*)take((size_t)K * 4);
    double* yrv     = (double*)take((size_t)N * 8);
    double* ynv     = (double*)take((size_t)N * 8);
    (void)ws_size;

    hipMemsetAsync(counts, 0, (size_t)N * 4, stream);
    hipMemsetAsync(rankcnt, 0, (size_t)N * 4, stream);

    concat_kernel<<<(N * 64 + 255) / 256, 256, 0, stream>>>(f0, f1, xA, N);
    count_kernel<<<(E + 255) / 256, 256, 0, stream>>>(dst, counts, E);
    scan_kernel<<<1, 1024, 0, stream>>>(counts, offs, N, E);
    fill_kernel<<<(E + 255) / 256, 256, 0, stream>>>(dst, offs, counts, csr, E);
    bsort_kernel<<<(N + 255) / 256, 256, 0, stream>>>(csr, offs, src, N);

    float* xcur = xA;
    float* xnext = xB;
    for (int i = 0; i < L; ++i) {
        segsum_kernel<<<N / 4, 256, 0, stream>>>(xcur, csr, offs, agg, N);
        gemm_two_kernel<<<dim3(256 / GBN, N / GBM), 256, 0, stream>>>(
            xcur, agg, Wr + (size_t)i * 65536, Wn + (size_t)i * 65536,
            b + (size_t)i * 256, xnext, N);
        float* tmp = xcur; xcur = xnext; xnext = tmp;
    }
    // xcur == x3
    dot_kernel<<<N / 4, 256, 0, stream>>>(xcur, Wpr, Wpn, yrv, ynv, N);
    score_gather_kernel<<<N / 256, 256, 0, stream>>>(yrv, ynv, csr, offs, bp, sc, keys, N);
    rank_count_kernel<<<dim3(N / RTJ, N / RTI), 256, 0, stream>>>(keys, rankcnt, N);
    rank_scatter_kernel<<<(N + 255) / 256, 256, 0, stream>>>(rankcnt, sc, perm, topd, N, K);
    out_kernel<<<K / 4, 256, 0, stream>>>(xcur, perm, topd, Wc, bc, out, K);
}

// Round 5
// 813.547 us; speedup vs baseline: 2.3651x; 1.0044x over previous
//
#include <hip/hip_runtime.h>
#include <hip/hip_bf16.h>
#include <math.h>
#include <stdint.h>

// N = 32768 nodes, D = 256 features, E = 524288 edges, L = 3 layers,
// K = 16384 (top-k), C = 11 classes.

// ---------------------------------------------------------------------------
// 1. concat f0,f1 -> x0 [N][256]
// ---------------------------------------------------------------------------
__global__ __launch_bounds__(256) void concat_kernel(const float* __restrict__ f0,
                                                     const float* __restrict__ f1,
                                                     float* __restrict__ x,
                                                     int N) {
    int gid = blockIdx.x * blockDim.x + threadIdx.x;  // one float4 per thread
    int total = N * 64;                               // 64 float4 per row
    if (gid >= total) return;
    int n = gid >> 6;
    int q = gid & 63;
    float4 v;
    if (q < 32) v = *(const float4*)(f0 + (size_t)n * 128 + q * 4);
    else        v = *(const float4*)(f1 + (size_t)n * 128 + (q - 32) * 4);
    *(float4*)(x + (size_t)n * 256 + q * 4) = v;
}

// ---------------------------------------------------------------------------
// 2a. histogram of dst
// ---------------------------------------------------------------------------
__global__ __launch_bounds__(256) void count_kernel(const int* __restrict__ dst,
                                                    int* __restrict__ counts, int E) {
    int e = blockIdx.x * blockDim.x + threadIdx.x;
    if (e < E) atomicAdd(&counts[dst[e]], 1);
}

// ---------------------------------------------------------------------------
// 2b. exclusive scan of counts -> offsets[N+1]; zero counts (reused as cursor)
// ---------------------------------------------------------------------------
__global__ __launch_bounds__(1024) void scan_kernel(int* __restrict__ counts,
                                                    int* __restrict__ offs,
                                                    int N, int E) {
    __shared__ int s[1024];
    int t = threadIdx.x;
    int base = t * 32;
    int local[32];
    int sum = 0;
    #pragma unroll
    for (int j = 0; j < 32; ++j) { local[j] = counts[base + j]; sum += local[j]; }
    s[t] = sum;
    __syncthreads();
    for (int off = 1; off < 1024; off <<= 1) {
        int other = (t >= off) ? s[t - off] : 0;
        __syncthreads();
        s[t] += other;
        __syncthreads();
    }
    int run = s[t] - sum;  // exclusive base for this thread
    #pragma unroll
    for (int j = 0; j < 32; ++j) {
        offs[base + j] = run;
        run += local[j];
        counts[base + j] = 0;   // reset: reused as cursor in fill_kernel
    }
    if (t == 1023) offs[N] = E;
}

// ---------------------------------------------------------------------------
// 2c. scatter edge ids into CSR buckets
// ---------------------------------------------------------------------------
__global__ __launch_bounds__(256) void fill_kernel(const int* __restrict__ dst,
                                                   const int* __restrict__ offs,
                                                   int* __restrict__ cursor,
                                                   int* __restrict__ csr, int E) {
    int e = blockIdx.x * blockDim.x + threadIdx.x;
    if (e >= E) return;
    int d = dst[e];
    int pos = offs[d] + atomicAdd(&cursor[d], 1);
    csr[pos] = e;
}

// ---------------------------------------------------------------------------
// 2d. per-bucket insertion sort by edge id (deterministic), map edge->src
// ---------------------------------------------------------------------------
__global__ __launch_bounds__(256) void bsort_kernel(int* __restrict__ csr,
                                                    const int* __restrict__ offs,
                                                    const int* __restrict__ src,
                                                    int N) {
    int i = blockIdx.x * blockDim.x + threadIdx.x;
    if (i >= N) return;
    int beg = offs[i], end = offs[i + 1];
    for (int a = beg + 1; a < end; ++a) {
        int v = csr[a];
        int b = a - 1;
        while (b >= beg && csr[b] > v) { csr[b + 1] = csr[b]; --b; }
        csr[b + 1] = v;
    }
    for (int p = beg; p < end; ++p) csr[p] = src[csr[p]];
}

// ---------------------------------------------------------------------------
// 3. segment sum: agg[n][:] = sum over csr bucket of x[src][:]
// ---------------------------------------------------------------------------
__global__ __launch_bounds__(256) void segsum_kernel(const float* __restrict__ X,
                                                     const int* __restrict__ csr,
                                                     const int* __restrict__ offs,
                                                     float* __restrict__ AGG, int N) {
    int w = threadIdx.x >> 6;
    int lane = threadIdx.x & 63;
    int n = blockIdx.x * 4 + w;
    if (n >= N) return;
    int beg = offs[n], end = offs[n + 1];
    float4 acc = make_float4(0.f, 0.f, 0.f, 0.f);
    for (int p = beg; p < end; ++p) {
        int s = csr[p];
        float4 v = *(const float4*)(X + (size_t)s * 256 + lane * 4);
        acc.x += v.x; acc.y += v.y; acc.z += v.z; acc.w += v.w;
    }
    *(float4*)(AGG + (size_t)n * 256 + lane * 4) = acc;
}

// ---------------------------------------------------------------------------
// 4. fused GEMM: Y = relu(X @ W1 + G @ W2 + bias)   [N,512-split] x [512,256]
//    128x128 tile, BK=32, 256 threads, 4x(4x4) quadrant micro-tile,
//    register double-buffered global->LDS staging.
// ---------------------------------------------------------------------------
#define GBM 128
#define GBN 128
#define GBK 32

#define GEMM_LOAD_STAGE(kt)                                                          \
    {                                                                                \
        const int kb = (kt) * GBK;                                                   \
        const float* Asrc = (kb < 256) ? X : G;                                      \
        const float* Wsrc = (kb < 256) ? W1 : W2;                                    \
        const int kloc = kb & 255;                                                   \
        a_st0 = *(const float4*)(Asrc + (size_t)(rowBase + ar) * 256 + kloc + ak);   \
        a_st1 = *(const float4*)(Asrc + (size_t)(rowBase + ar + 64) * 256 + kloc + ak); \
        a_st2 = *(const float4*)(Asrc + (size_t)(rowBase + ar) * 256 + kloc + 16 + ak); \
        a_st3 = *(const float4*)(Asrc + (size_t)(rowBase + ar + 64) * 256 + kloc + 16 + ak); \
        w_st0 = *(const float4*)(Wsrc + (size_t)(kloc + wk) * 256 + colBase + wc);   \
        w_st1 = *(const float4*)(Wsrc + (size_t)(kloc + wk + 8) * 256 + colBase + wc); \
        w_st2 = *(const float4*)(Wsrc + (size_t)(kloc + wk + 16) * 256 + colBase + wc); \
        w_st3 = *(const float4*)(Wsrc + (size_t)(kloc + wk + 24) * 256 + colBase + wc); \
    }

__global__ __launch_bounds__(256) void gemm_two_kernel(const float* __restrict__ X,
                                                       const float* __restrict__ G,
                                                       const float* __restrict__ W1,
                                                       const float* __restrict__ W2,
                                                       const float* __restrict__ bias,
                                                       float* __restrict__ Y) {
    __shared__ float As[GBK][GBM + 4];
    __shared__ float Ws[GBK][GBN + 4];
    const int tid = threadIdx.x;
    const int tcol = tid & 15;          // 0..15 -> cols tcol*4 and 64+tcol*4
    const int trow = tid >> 4;          // 0..15 -> rows trow*4 and 64+trow*4
    const int rowBase = blockIdx.y * GBM;
    const int colBase = blockIdx.x * GBN;

    const int ar = tid >> 2;            // A stage row (0..63), +64 for 2nd
    const int ak = (tid & 3) * 4;       // A stage k offset (float4), +16 for 2nd
    const int wk = tid >> 5;            // W stage k row (0..7), +8/+16/+24
    const int wc = (tid & 31) * 4;      // W stage col offset (float4)

    float4 a_st0, a_st1, a_st2, a_st3, w_st0, w_st1, w_st2, w_st3;

    // acc[h*2+g][i][j]: row half h, col half g
    float acc[4][4][4];
    #pragma unroll
    for (int q = 0; q < 4; ++q)
        #pragma unroll
        for (int i = 0; i < 4; ++i)
            #pragma unroll
            for (int j = 0; j < 4; ++j) acc[q][i][j] = 0.f;

    GEMM_LOAD_STAGE(0);

    for (int kt = 0; kt < 512 / GBK; ++kt) {
        __syncthreads();   // previous tile fully consumed
        #pragma unroll
        for (int j = 0; j < 4; ++j) {
            As[ak + j][ar]           = ((const float*)&a_st0)[j];
            As[ak + j][ar + 64]      = ((const float*)&a_st1)[j];
            As[16 + ak + j][ar]      = ((const float*)&a_st2)[j];
            As[16 + ak + j][ar + 64] = ((const float*)&a_st3)[j];
        }
        *(float4*)&Ws[wk][wc]      = w_st0;
        *(float4*)&Ws[wk + 8][wc]  = w_st1;
        *(float4*)&Ws[wk + 16][wc] = w_st2;
        *(float4*)&Ws[wk + 24][wc] = w_st3;
        __syncthreads();
        if (kt < 512 / GBK - 1) GEMM_LOAD_STAGE(kt + 1);  // overlap with compute
        #pragma unroll
        for (int kk = 0; kk < GBK; ++kk) {
            float a0[4], a1[4], w0[4], w1[4];
            *(float4*)a0 = *(const float4*)&As[kk][trow * 4];
            *(float4*)a1 = *(const float4*)&As[kk][64 + trow * 4];
            *(float4*)w0 = *(const float4*)&Ws[kk][tcol * 4];
            *(float4*)w1 = *(const float4*)&Ws[kk][64 + tcol * 4];
            #pragma unroll
            for (int i = 0; i < 4; ++i)
                #pragma unroll
                for (int j = 0; j < 4; ++j) {
                    acc[0][i][j] = fmaf(a0[i], w0[j], acc[0][i][j]);
                    acc[1][i][j] = fmaf(a0[i], w1[j], acc[1][i][j]);
                    acc[2][i][j] = fmaf(a1[i], w0[j], acc[2][i][j]);
                    acc[3][i][j] = fmaf(a1[i], w1[j], acc[3][i][j]);
                }
        }
    }
    #pragma unroll
    for (int h = 0; h < 2; ++h) {
        #pragma unroll
        for (int i = 0; i < 4; ++i) {
            const int row = rowBase + h * 64 + trow * 4 + i;
            #pragma unroll
            for (int g = 0; g < 2; ++g) {
                const int colb = colBase + g * 64 + tcol * 4;
                float o[4];
                #pragma unroll
                for (int j = 0; j < 4; ++j)
                    o[j] = fmaxf(acc[h * 2 + g][i][j] + bias[colb + j], 0.f);
                *(float4*)(Y + (size_t)row * 256 + colb) = *(const float4*)&o[0];
            }
        }
    }
}

// ---------------------------------------------------------------------------
// 5a. per-node dots: yr[n] = x3[n].Wpr, yn[n] = x3[n].Wpn   (f64)
// ---------------------------------------------------------------------------
__global__ __launch_bounds__(256) void dot_kernel(const float* __restrict__ X3,
                                                  const float* __restrict__ Wpr,
                                                  const float* __restrict__ Wpn,
                                                  double* __restrict__ yr,
                                                  double* __restrict__ yn, int N) {
    int w = threadIdx.x >> 6;
    int lane = threadIdx.x & 63;
    int n = blockIdx.x * 4 + w;
    if (n >= N) return;
    float4 xv = *(const float4*)(X3 + (size_t)n * 256 + lane * 4);
    float4 wr = *(const float4*)(Wpr + lane * 4);
    float4 wn = *(const float4*)(Wpn + lane * 4);
    double dr = (double)xv.x * wr.x + (double)xv.y * wr.y +
                (double)xv.z * wr.z + (double)xv.w * wr.w;
    double dn = (double)xv.x * wn.x + (double)xv.y * wn.y +
                (double)xv.z * wn.z + (double)xv.w * wn.w;
    #pragma unroll
    for (int o = 32; o > 0; o >>= 1) {
        dr += __shfl_down(dr, o, 64);
        dn += __shfl_down(dn, o, 64);
    }
    if (lane == 0) { yr[n] = dr; yn[n] = dn; }
}

// ---------------------------------------------------------------------------
// 5b. score[n] = yr[n] + sum_{bucket} yn[src] + bp; emit order-preserving key
// ---------------------------------------------------------------------------
__global__ __launch_bounds__(256) void score_gather_kernel(
        const double* __restrict__ yr, const double* __restrict__ yn,
        const int* __restrict__ csr, const int* __restrict__ offs,
        const float* __restrict__ bp,
        double* __restrict__ sc, unsigned long long* __restrict__ keys, int N) {
    int n = blockIdx.x * blockDim.x + threadIdx.x;
    if (n >= N) return;
    double s = yr[n] + (double)bp[0];
    int beg = offs[n], end = offs[n + 1];
    for (int p = beg; p < end; ++p) s += yn[csr[p]];
    sc[n] = s;
    long long sb = __double_as_longlong(s);
    keys[n] = (sb < 0) ? ~(unsigned long long)sb
                       : ((unsigned long long)sb | 0x8000000000000000ULL);
}

// ---------------------------------------------------------------------------
// 6a. tiled exact rank-count on uint64 keys.
//     RTI=1024 i (4 regs/thread) x RTJ=512 j (LDS) -> 2048 blocks (8/CU).
// ---------------------------------------------------------------------------
#define RTI 1024
#define RTJ 512
__global__ __launch_bounds__(256) void rank_count_kernel(
        const unsigned long long* __restrict__ keys,
        int* __restrict__ rankcnt, int N) {
    __shared__ __align__(16) unsigned long long sk[RTJ];
    const int tid = threadIdx.x;
    const int ibase = blockIdx.y * RTI;
    const int jbase = blockIdx.x * RTJ;

    unsigned long long ki[4];
    #pragma unroll
    for (int r = 0; r < 4; ++r) ki[r] = keys[ibase + r * 256 + tid];
    for (int t = tid; t < RTJ; t += 256) sk[t] = keys[jbase + t];
    __syncthreads();

    int cnt[4] = {0, 0, 0, 0};
    if (jbase + RTJ <= ibase) {
        // all j < i : tie counts -> kj >= ki
        for (int u = 0; u < RTJ; u += 8) {
            ulonglong2 p0 = *(const ulonglong2*)&sk[u];
            ulonglong2 p1 = *(const ulonglong2*)&sk[u + 2];
            ulonglong2 p2 = *(const ulonglong2*)&sk[u + 4];
            ulonglong2 p3 = *(const ulonglong2*)&sk[u + 6];
            #pragma unroll
            for (int r = 0; r < 4; ++r) {
                cnt[r] += (int)(p0.x >= ki[r]) + (int)(p0.y >= ki[r])
                        + (int)(p1.x >= ki[r]) + (int)(p1.y >= ki[r])
                        + (int)(p2.x >= ki[r]) + (int)(p2.y >= ki[r])
                        + (int)(p3.x >= ki[r]) + (int)(p3.y >= ki[r]);
            }
        }
    } else if (jbase >= ibase + RTI) {
        // all j > i : tie doesn't count -> kj > ki
        for (int u = 0; u < RTJ; u += 8) {
            ulonglong2 p0 = *(const ulonglong2*)&sk[u];
            ulonglong2 p1 = *(const ulonglong2*)&sk[u + 2];
            ulonglong2 p2 = *(const ulonglong2*)&sk[u + 4];
            ulonglong2 p3 = *(const ulonglong2*)&sk[u + 6];
            #pragma unroll
            for (int r = 0; r < 4; ++r) {
                cnt[r] += (int)(p0.x > ki[r]) + (int)(p0.y > ki[r])
                        + (int)(p1.x > ki[r]) + (int)(p1.y > ki[r])
                        + (int)(p2.x > ki[r]) + (int)(p2.y > ki[r])
                        + (int)(p3.x > ki[r]) + (int)(p3.y > ki[r]);
            }
        }
    } else {
        // diagonal tile: full three-term compare (u < thr[r]  <=>  j < i)
        int thr[4];
        #pragma unroll
        for (int r = 0; r < 4; ++r) thr[r] = ibase + r * 256 + tid - jbase;
        for (int u = 0; u < RTJ; ++u) {
            unsigned long long kj = sk[u];
            #pragma unroll
            for (int r = 0; r < 4; ++r)
                cnt[r] += (kj > ki[r]) || (kj == ki[r] && u < thr[r]);
        }
    }
    #pragma unroll
    for (int r = 0; r < 4; ++r)
        atomicAdd(&rankcnt[ibase + r * 256 + tid], cnt[r]);
}

// ---------------------------------------------------------------------------
// 6b. scatter by rank
// ---------------------------------------------------------------------------
__global__ __launch_bounds__(256) void rank_scatter_kernel(
        const int* __restrict__ rankcnt,
        const double* __restrict__ sc,
        int* __restrict__ perm,
        double* __restrict__ topd, int N, int K) {
    int i = blockIdx.x * blockDim.x + threadIdx.x;
    if (i >= N) return;
    int rank = rankcnt[i];
    if (rank < K) { perm[rank] = i; topd[rank] = sc[i]; }
}

// ---------------------------------------------------------------------------
// 7. head: out[r] = relu(x3[perm[r]] * tanh(score_r)) @ Wc + bc  (f64 accum)
// ---------------------------------------------------------------------------
__global__ __launch_bounds__(256) void out_kernel(const float* __restrict__ X3,
                                                  const int* __restrict__ perm,
                                                  const double* __restrict__ topd,
                                                  const float* __restrict__ Wc,
                                                  const float* __restrict__ bc,
                                                  float* __restrict__ out, int K) {
    int w = threadIdx.x >> 6;
    int lane = threadIdx.x & 63;
    int r = blockIdx.x * 4 + w;
    if (r >= K) return;
    int p = perm[r];
    double t = tanh(topd[r]);
    float4 xv = *(const float4*)(X3 + (size_t)p * 256 + lane * 4);
    double xp[4];
    xp[0] = (double)xv.x * t; xp[1] = (double)xv.y * t;
    xp[2] = (double)xv.z * t; xp[3] = (double)xv.w * t;
    #pragma unroll
    for (int j = 0; j < 4; ++j) xp[j] = xp[j] > 0.0 ? xp[j] : 0.0;
    double acc[11];
    #pragma unroll
    for (int c = 0; c < 11; ++c) acc[c] = 0.0;
    #pragma unroll
    for (int j = 0; j < 4; ++j) {
        const float* wrow = Wc + (size_t)(lane * 4 + j) * 11;
        #pragma unroll
        for (int c = 0; c < 11; ++c) acc[c] += xp[j] * (double)wrow[c];
    }
    #pragma unroll
    for (int c = 0; c < 11; ++c) {
        double v = acc[c];
        #pragma unroll
        for (int o = 32; o > 0; o >>= 1) v += __shfl_down(v, o, 64);
        if (lane == 0) out[(size_t)r * 11 + c] = (float)(v + (double)bc[c]);
    }
}

// ---------------------------------------------------------------------------
// launch
// ---------------------------------------------------------------------------
extern "C" void kernel_launch(void* const* d_in, const int* in_sizes, int n_in,
                              void* d_out, int out_size, void* d_ws, size_t ws_size,
                              hipStream_t stream) {
    const float* f0  = (const float*)d_in[0];
    const float* f1  = (const float*)d_in[1];
    const int*   ei  = (const int*)d_in[2];
    const float* Wr  = (const float*)d_in[3];
    const float* Wn  = (const float*)d_in[4];
    const float* b   = (const float*)d_in[5];
    const float* Wpr = (const float*)d_in[6];
    const float* Wpn = (const float*)d_in[7];
    const float* bp  = (const float*)d_in[8];
    const float* Wc  = (const float*)d_in[9];
    const float* bc  = (const float*)d_in[10];
    float* out = (float*)d_out;

    const int N = in_sizes[0] / 128;   // 32768
    const int E = in_sizes[2] / 2;     // 524288
    const int K = (N + 1) / 2;         // 16384
    const int L = in_sizes[5] / 256;   // 3 layers

    const int* src = ei;
    const int* dst = ei + E;

    // workspace layout (256B aligned slices)
    char* p = (char*)d_ws;
    auto take = [&](size_t bytes) {
        char* r = p;
        p += (bytes + 255) & ~(size_t)255;
        return r;
    };
    float*  xA      = (float*)take((size_t)N * 256 * 4);
    float*  xB      = (float*)take((size_t)N * 256 * 4);
    float*  agg     = (float*)take((size_t)N * 256 * 4);
    int*    counts  = (int*)take((size_t)N * 4);
    int*    offs    = (int*)take((size_t)(N + 1) * 4);
    int*    csr     = (int*)take((size_t)E * 4);
    double* sc      = (double*)take((size_t)N * 8);
    unsigned long long* keys = (unsigned long long*)take((size_t)N * 8);
    int*    rankcnt = (int*)take((size_t)N * 4);
    double* topd    = (double*)take((size_t)K * 8);
    int*    perm    = (int*)take((size_t)K * 4);
    double* yrv     = (double*)take((size_t)N * 8);
    double* ynv     = (double*)take((size_t)N * 8);
    (void)ws_size;

    hipMemsetAsync(counts, 0, (size_t)N * 4, stream);
    hipMemsetAsync(rankcnt, 0, (size_t)N * 4, stream);

    concat_kernel<<<(N * 64 + 255) / 256, 256, 0, stream>>>(f0, f1, xA, N);
    count_kernel<<<(E + 255) / 256, 256, 0, stream>>>(dst, counts, E);
    scan_kernel<<<1, 1024, 0, stream>>>(counts, offs, N, E);
    fill_kernel<<<(E + 255) / 256, 256, 0, stream>>>(dst, offs, counts, csr, E);
    bsort_kernel<<<(N + 255) / 256, 256, 0, stream>>>(csr, offs, src, N);

    float* xcur = xA;
    float* xnext = xB;
    for (int i = 0; i < L; ++i) {
        segsum_kernel<<<N / 4, 256, 0, stream>>>(xcur, csr, offs, agg, N);
        gemm_two_kernel<<<dim3(256 / GBN, N / GBM), 256, 0, stream>>>(
            xcur, agg, Wr + (size_t)i * 65536, Wn + (size_t)i * 65536,
            b + (size_t)i * 256, xnext);
        float* tmp = xcur; xcur = xnext; xnext = tmp;
    }
    // xcur == x3
    dot_kernel<<<N / 4, 256, 0, stream>>>(xcur, Wpr, Wpn, yrv, ynv, N);
    score_gather_kernel<<<N / 256, 256, 0, stream>>>(yrv, ynv, csr, offs, bp, sc, keys, N);
    rank_count_kernel<<<dim3(N / RTJ, N / RTI), 256, 0, stream>>>(keys, rankcnt, N);
    rank_scatter_kernel<<<(N + 255) / 256, 256, 0, stream>>>(rankcnt, sc, perm, topd, N, K);
    out_kernel<<<K / 4, 256, 0, stream>>>(xcur, perm, topd, Wc, bc, out, K);
}